// Round 7
// baseline (164.691 us; speedup 1.0000x reference)
//
#include <hip/hip_runtime.h>

// VQ-VAE eval forward, MFMA bf16x3-split path (fp32-faithful distances).
// B=64, D=64, H=32, W=32 -> N=65536 queries dim 64; K=1024 codes.
// dist(q,c) = ||e_c||^2 - 2 <x_q, e_c>  (||x||^2 dropped: per-query constant).
// <x,e> via 6 bf16 MFMA products: x=xh+xm+xl exactly; keep hh,hm,mh,mm,hl,lh.
//
// R7 = R6 structure (76us vq_main, separate vq_final: fused finalize proven
// to cost ~45us structure-independent across R1/R2/R4/R5) with the per-block
// codebook split moved to vq_prep: ws_split holds the EXACT swizzled LDS
// image, so vq_main staging is 6 global dwordx4 -> 6 linear ds_write_b128
// per thread (no split VALU in the 512-block hot path). R2 proved ws_split
// L2 reads are not a slow path (786MB read, same floor). Values bit-identical
// (same f2bf chain in prep; norm chain untouched) -> same indices/absmax.

#define DIMS 64
#define K_CODES 1024
#define N_QUERIES 65536
#define HW 1024
#define TOTAL_ELEMS 4194304
#define PLANE 4096          // shorts per plane in a code-tile buffer
#define TILE_SHORTS 12288   // 3 * PLANE
#define SPLIT_OFF 16384     // byte offset of split buffer in ws
#define SPLIT_BYTES 393216  // 16 tiles * 24576 B

typedef __attribute__((ext_vector_type(8))) short v8s;   // 8 bf16 = 4 VGPR (A/B frag)
typedef __attribute__((ext_vector_type(4))) float f32x4; // C/D frag

__device__ inline unsigned short f2bf(float x) {
    union { float f; unsigned u; } v; v.f = x;
    unsigned r = v.u + 0x7fff + ((v.u >> 16) & 1);  // RNE
    return (unsigned short)(r >> 16);
}
__device__ inline float bf2f(unsigned short h) {
    union { unsigned u; float f; } v; v.u = ((unsigned)h) << 16; return v.f;
}

// ---------------- Kernel A: norms + swizzled split planes + zeroing ----------------
// 4 blocks x 256 threads, one thread per code. Norm summation chain EXACTLY as
// R0/R6 (bit-identical norms -> identical tie behavior). Split layout per tile
// t (64 codes): [p (3 planes)][octet o (8)][slot = c ^ (o<<1)][8 bf16] ==
// the swizzled LDS tile image vq_main stages verbatim.
__global__ void vq_prep(const float* __restrict__ emb, float* __restrict__ ws_norm,
                        int* __restrict__ ws_flags, float* __restrict__ ws_loss,
                        unsigned short* __restrict__ ws_split) {
    int k = blockIdx.x * 256 + threadIdx.x;  // 0..1023
    const float4* row = (const float4*)(emb + k * DIMS);
    float s = 0.f;
#pragma unroll
    for (int i = 0; i < 16; ++i) {
        float4 v = row[i];
        s += v.x * v.x + v.y * v.y + v.z * v.z + v.w * v.w;
    }
    ws_norm[k] = s;
    ws_flags[k] = 0;
    if (k == 0) *ws_loss = 0.f;

    if (ws_split) {
        const int t = k >> 6, c = k & 63;
        unsigned short* tb = ws_split + t * TILE_SHORTS;
#pragma unroll
        for (int o = 0; o < 8; ++o) {
            float4 v0 = row[o * 2], v1 = row[o * 2 + 1];
            float xs[8] = {v0.x, v0.y, v0.z, v0.w, v1.x, v1.y, v1.z, v1.w};
            unsigned h[8], m[8], l[8];
#pragma unroll
            for (int j = 0; j < 8; ++j) {
                float x = xs[j];
                unsigned short hh = f2bf(x);  float r1 = x - bf2f(hh);
                unsigned short mh = f2bf(r1); float r2 = r1 - bf2f(mh);
                h[j] = hh; m[j] = mh; l[j] = f2bf(r2);
            }
            int slot = c ^ (o << 1);
            int base = (o * 64 + slot) * 8;  // shorts; 16B-aligned
            uint4 uh = {h[0] | (h[1] << 16), h[2] | (h[3] << 16),
                        h[4] | (h[5] << 16), h[6] | (h[7] << 16)};
            uint4 um = {m[0] | (m[1] << 16), m[2] | (m[3] << 16),
                        m[4] | (m[5] << 16), m[6] | (m[7] << 16)};
            uint4 ul = {l[0] | (l[1] << 16), l[2] | (l[3] << 16),
                        l[4] | (l[5] << 16), l[6] | (l[7] << 16)};
            *(uint4*)(tb + 0 * PLANE + base) = uh;
            *(uint4*)(tb + 1 * PLANE + base) = um;
            *(uint4*)(tb + 2 * PLANE + base) = ul;
        }
    }
}

#define MFMA16(A_, B_, C_) __builtin_amdgcn_mfma_f32_16x16x32_bf16(A_, B_, C_, 0, 0, 0)

// ---------------- Kernel B: MFMA distances + argmin + gather + loss ----------------
// 512 blocks x 256 threads (4 waves), 2 blocks/CU. Block = 128 queries; wave =
// 32 queries (2 row-tiles of 16), each wave scans ALL 1024 codes in 16 tiles of 64.
template <bool PRESPLIT>
__global__ __launch_bounds__(256, 2)
void vq_main(const float* __restrict__ z_e, const float* __restrict__ emb,
             const float* __restrict__ ws_norm, int* __restrict__ ws_flags,
             float* __restrict__ ws_loss, const unsigned short* __restrict__ ws_split,
             float* __restrict__ out) {
    // Double-buffered code tile, frag-ready: [buf][plane p][octet o][slot][8 bf16]
    // slot = code ^ (o<<1)  (bank-conflict swizzle on code bits 1-3)
    __shared__ unsigned short ldsB[2][3 * PLANE];  // 48 KB
    __shared__ int   fIdx[128];
    __shared__ float wsum[4];

    const int tid  = threadIdx.x;
    const int lane = tid & 63;
    const int wid  = tid >> 6;
    const int qbase = blockIdx.x * 128;
    const int b    = qbase >> 10;          // batch index (uniform per block)
    const int hwb  = qbase & (HW - 1);

    const int col  = lane & 15;  // m (A) / n (B) within 16-tile
    const int qd   = lane >> 4;  // quad -> k-octet selector

    // ---- Build A fragments from global (coalesced), split into 3 bf16 planes ----
    v8s afr[2][2][3];
    {
        const float* zb = z_e + b * (DIMS * HW);
#pragma unroll
        for (int rt = 0; rt < 2; ++rt) {
            int hwq = hwb + wid * 32 + rt * 16 + col;
#pragma unroll
            for (int kc = 0; kc < 2; ++kc) {
                int dbase = kc * 32 + qd * 8;
#pragma unroll
                for (int j = 0; j < 8; ++j) {
                    float x = zb[(dbase + j) * HW + hwq];
                    unsigned short h = f2bf(x);  float r1 = x - bf2f(h);
                    unsigned short m = f2bf(r1); float r2 = r1 - bf2f(m);
                    afr[rt][kc][0][j] = (short)h;
                    afr[rt][kc][1][j] = (short)m;
                    afr[rt][kc][2][j] = (short)f2bf(r2);
                }
            }
        }
    }

    float bestv[2][4];
    int   besti[2][4];
#pragma unroll
    for (int rt = 0; rt < 2; ++rt)
#pragma unroll
        for (int r = 0; r < 4; ++r) { bestv[rt][r] = 3.4e38f; besti[rt][r] = 0; }

    // ---- Staging ----
    // PRESPLIT: tile t is a 24KB swizzled LDS image in ws_split (L2-resident).
    //   6 x dwordx4 global loads -> regs -> 6 linear (conflict-free) ds_write_b128.
    // Fallback: R6's in-block split-from-fp32.
    uint4  pregs[6];
    float4 regs[4];
    auto stage_loads = [&](int t) {
        if constexpr (PRESPLIT) {
            const uint4* src = (const uint4*)(ws_split + t * TILE_SHORTS);
#pragma unroll
            for (int i = 0; i < 6; ++i) pregs[i] = src[256 * i + tid];
        } else {
            const float4* src = (const float4*)(emb + t * 64 * DIMS);
#pragma unroll
            for (int i = 0; i < 4; ++i) regs[i] = src[tid + 256 * i];
        }
    };
    auto stage_write = [&](int bb) {
        if constexpr (PRESPLIT) {
            uint4* dst = (uint4*)&ldsB[bb][0];
#pragma unroll
            for (int i = 0; i < 6; ++i) dst[256 * i + tid] = pregs[i];
        } else {
            unsigned short* dst = &ldsB[bb][0];
#pragma unroll
            for (int i = 0; i < 4; ++i) {
                int e    = (tid + 256 * i) * 4;
                int code = e >> 6;
                int d    = e & 63;
                int o    = d >> 3;
                int sub  = d & 7;
                float xs[4] = {regs[i].x, regs[i].y, regs[i].z, regs[i].w};
                unsigned short h[4], mm_[4], l[4];
#pragma unroll
                for (int q = 0; q < 4; ++q) {
                    float x = xs[q];
                    unsigned short hh = f2bf(x);  float r1 = x - bf2f(hh);
                    unsigned short mh = f2bf(r1); float r2 = r1 - bf2f(mh);
                    h[q] = hh; mm_[q] = mh; l[q] = f2bf(r2);
                }
                int base = (o * 64 + (code ^ (o << 1))) * 8 + sub;  // swizzled slot
                uint2 uh, um, ul;
                uh.x = (unsigned)h[0]   | ((unsigned)h[1] << 16);
                uh.y = (unsigned)h[2]   | ((unsigned)h[3] << 16);
                um.x = (unsigned)mm_[0] | ((unsigned)mm_[1] << 16);
                um.y = (unsigned)mm_[2] | ((unsigned)mm_[3] << 16);
                ul.x = (unsigned)l[0]   | ((unsigned)l[1] << 16);
                ul.y = (unsigned)l[2]   | ((unsigned)l[3] << 16);
                *(uint2*)(dst + base)             = uh;
                *(uint2*)(dst + PLANE + base)     = um;
                *(uint2*)(dst + 2 * PLANE + base) = ul;
            }
        }
    };

    stage_loads(0);
    stage_write(0);
    __syncthreads();

    for (int t = 0; t < 16; ++t) {
        const int cur = t & 1;
        if (t < 15) stage_loads(t + 1);
        const unsigned short* bufc = &ldsB[cur][0];
#pragma unroll
        for (int cs = 0; cs < 4; ++cs) {
            float nrm = ws_norm[t * 64 + cs * 16 + col];
            // B-frags: B[n=col][k=qd*8+j], octet = kc*4+qd, swizzled slot.
            v8s bfr[2][3];
#pragma unroll
            for (int kc = 0; kc < 2; ++kc) {
                int oct  = kc * 4 + qd;
                int slot = (cs * 16 + col) ^ (oct << 1);
#pragma unroll
                for (int p = 0; p < 3; ++p)
                    bfr[kc][p] = *(const v8s*)(bufc + p * PLANE + (oct * 64 + slot) * 8);
            }
            f32x4 acc0 = {0.f, 0.f, 0.f, 0.f};
            f32x4 acc1 = {0.f, 0.f, 0.f, 0.f};
#pragma unroll
            for (int kc = 0; kc < 2; ++kc) {
                acc0 = MFMA16(afr[0][kc][0], bfr[kc][0], acc0);  // hh
                acc1 = MFMA16(afr[1][kc][0], bfr[kc][0], acc1);
                acc0 = MFMA16(afr[0][kc][0], bfr[kc][1], acc0);  // hm
                acc1 = MFMA16(afr[1][kc][0], bfr[kc][1], acc1);
                acc0 = MFMA16(afr[0][kc][1], bfr[kc][0], acc0);  // mh
                acc1 = MFMA16(afr[1][kc][1], bfr[kc][0], acc1);
                acc0 = MFMA16(afr[0][kc][1], bfr[kc][1], acc0);  // mm
                acc1 = MFMA16(afr[1][kc][1], bfr[kc][1], acc1);
                acc0 = MFMA16(afr[0][kc][0], bfr[kc][2], acc0);  // hl
                acc1 = MFMA16(afr[1][kc][0], bfr[kc][2], acc1);
                acc0 = MFMA16(afr[0][kc][2], bfr[kc][0], acc0);  // lh
                acc1 = MFMA16(afr[1][kc][2], bfr[kc][0], acc1);
            }
            int cbase = t * 64 + cs * 16 + col;
#pragma unroll
            for (int r = 0; r < 4; ++r) {
                float d0 = fmaf(-2.f, acc0[r], nrm);
                if (d0 < bestv[0][r]) { bestv[0][r] = d0; besti[0][r] = cbase; }
                float d1 = fmaf(-2.f, acc1[r], nrm);
                if (d1 < bestv[1][r]) { bestv[1][r] = d1; besti[1][r] = cbase; }
            }
        }
        if (t < 15) stage_write(1 - cur);  // other buffer: safe while peers finish cur
        __syncthreads();
    }

    // ---- Final argmin across the 16 columns held by this quad's lanes ----
#pragma unroll
    for (int rt = 0; rt < 2; ++rt)
#pragma unroll
    for (int r = 0; r < 4; ++r) {
        float v = bestv[rt][r];
        int   idx = besti[rt][r];
#pragma unroll
        for (int m = 8; m >= 1; m >>= 1) {
            float ov = __shfl_xor(v, m, 64);
            int   oi = __shfl_xor(idx, m, 64);
            if (ov < v || (ov == v && oi < idx)) { v = ov; idx = oi; }
        }
        if (col == 0) {
            int q = wid * 32 + rt * 16 + qd * 4 + r;  // within block
            fIdx[q] = idx;
            out[TOTAL_ELEMS + 1 + qbase + q] = (float)idx;
            ws_flags[idx] = 1;  // benign race
        }
    }
    __syncthreads();

    // ---- Gather z_q, write coalesced, accumulate mse partial ----
    const int q  = tid & 127;
    const int dh = tid >> 7;  // even/odd dims
    const int n  = qbase + q;
    const int bb = n >> 10;
    const int hw = n & (HW - 1);
    const int myIdx = fIdx[q];
    const float* erow = emb + myIdx * DIMS;
    float lsum = 0.f;
#pragma unroll
    for (int it = 0; it < 32; ++it) {
        int d = it * 2 + dh;
        float v = erow[d];                         // random row, L2/L3-resident
        int   o = bb * (DIMS * HW) + d * HW + hw;  // consecutive q -> coalesced
        float ze = z_e[o];
        out[o] = v;
        float df = ze - v;
        lsum = fmaf(df, df, lsum);
    }
#pragma unroll
    for (int off = 32; off > 0; off >>= 1) lsum += __shfl_down(lsum, off, 64);
    if (lane == 0) wsum[wid] = lsum;
    __syncthreads();
    if (tid == 0) atomicAdd(ws_loss, wsum[0] + wsum[1] + wsum[2] + wsum[3]);
}

// ---------------- Kernel C: finalize loss + usage ----------------
__global__ void vq_final(const int* __restrict__ flags, const float* __restrict__ loss,
                         float* __restrict__ out) {
    __shared__ int cnt[256];
    int tid = threadIdx.x;
    int c = flags[tid] + flags[tid + 256] + flags[tid + 512] + flags[tid + 768];
    cnt[tid] = c;
    __syncthreads();
    for (int s = 128; s > 0; s >>= 1) {
        if (tid < s) cnt[tid] += cnt[tid + s];
        __syncthreads();
    }
    if (tid == 0) {
        out[TOTAL_ELEMS] = *loss / (float)TOTAL_ELEMS;
        out[TOTAL_ELEMS + 1 + N_QUERIES] = (float)cnt[0] / (float)K_CODES;
    }
}

extern "C" void kernel_launch(void* const* d_in, const int* in_sizes, int n_in,
                              void* d_out, int out_size, void* d_ws, size_t ws_size,
                              hipStream_t stream) {
    const float* z_e = (const float*)d_in[0];
    const float* emb = (const float*)d_in[1];
    float* out = (float*)d_out;
    float* ws_norm  = (float*)d_ws;
    int*   ws_flags = (int*)((char*)d_ws + 4096);
    float* ws_loss  = (float*)((char*)d_ws + 8192);

    bool presplit = ws_size >= (size_t)(SPLIT_OFF + SPLIT_BYTES);
    unsigned short* ws_split = presplit ? (unsigned short*)((char*)d_ws + SPLIT_OFF)
                                        : (unsigned short*)0;

    vq_prep<<<4, 256, 0, stream>>>(emb, ws_norm, ws_flags, ws_loss, ws_split);
    if (presplit)
        vq_main<true><<<512, 256, 0, stream>>>(z_e, emb, ws_norm, ws_flags, ws_loss,
                                               ws_split, out);
    else
        vq_main<false><<<512, 256, 0, stream>>>(z_e, emb, ws_norm, ws_flags, ws_loss,
                                                ws_split, out);
    vq_final<<<1, 256, 0, stream>>>(ws_flags, ws_loss, out);
}

// Round 8
// 138.652 us; speedup vs baseline: 1.1878x; 1.1878x over previous
//
#include <hip/hip_runtime.h>

// VQ-VAE eval forward, MFMA bf16x3-split path (fp32-faithful distances).
// B=64, D=64, H=32, W=32 -> N=65536 queries dim 64; K=1024 codes.
// dist(q,c) = ||e_c||^2 - 2 <x_q, e_c>  (||x||^2 dropped: per-query constant).
// <x,e> via 6 bf16 MFMA products: x=xh+xm+xl exactly; keep hh,hm,mh,mm,hl,lh.
//
// R8 = R6 (76us vq_main; best) with the MFMA shape switched 16x16x32 ->
// 32x32x16: same FLOPs at -18% matrix-pipe cycles (8.07 vs 2x4.85 cy, m119)
// and HALF the MFMA instruction slots (48 vs 96 per 64-code tile). The LDS
// tile layout/swizzle is unchanged and maps natively (B k-octet = kk*2 +
// lane_half). Two 12-deep acc chains (kk01 / kk23) preserve the ILP the old
// acc0/acc1 pair gave. Staging stays in-block-from-emb: R1/R2/R7 proved
// (3 structures) that bulk ws_split traffic in the hot loop costs +23-45us
// (R7: HBM fetch doubled, L2 thrash). Finalize stays a separate kernel:
// fused ticket finalize cost ~45us structure-independent (R1/R2/R4/R5 vs R6).
// Distance regrouping changes values only at fp32-reorder noise level; scan
// order and lowest-index tie-break preserved.

#define DIMS 64
#define K_CODES 1024
#define N_QUERIES 65536
#define HW 1024
#define TOTAL_ELEMS 4194304
#define PLANE 4096  // shorts per plane in a code-tile buffer: 8 octets * 64 slots * 8

typedef __attribute__((ext_vector_type(8))) short v8s;    // 8 bf16 = 4 VGPR (A/B frag)
typedef __attribute__((ext_vector_type(16))) float f32x16; // C/D frag (32x32)

__device__ inline unsigned short f2bf(float x) {
    union { float f; unsigned u; } v; v.f = x;
    unsigned r = v.u + 0x7fff + ((v.u >> 16) & 1);  // RNE
    return (unsigned short)(r >> 16);
}
__device__ inline float bf2f(unsigned short h) {
    union { unsigned u; float f; } v; v.u = ((unsigned)h) << 16; return v.f;
}

// ---------------- Kernel A: code norms + zero accumulators ----------------
__global__ void vq_prep(const float* __restrict__ emb, float* __restrict__ ws_norm,
                        int* __restrict__ ws_flags, float* __restrict__ ws_loss) {
    int k = blockIdx.x * 256 + threadIdx.x;  // 0..1023
    const float4* row = (const float4*)(emb + k * DIMS);
    float s = 0.f;
#pragma unroll
    for (int i = 0; i < 16; ++i) {
        float4 v = row[i];
        s += v.x * v.x + v.y * v.y + v.z * v.z + v.w * v.w;
    }
    ws_norm[k] = s;
    ws_flags[k] = 0;
    if (k == 0) *ws_loss = 0.f;
}

#define MFMA32(A_, B_, C_) __builtin_amdgcn_mfma_f32_32x32x16_bf16(A_, B_, C_, 0, 0, 0)

// ---------------- Kernel B: MFMA distances + argmin + gather + loss ----------------
// 512 blocks x 256 threads (4 waves), 2 blocks/CU. Block = 128 queries; wave =
// 32 queries (one 32-row MFMA tile), each wave scans ALL 1024 codes in 16
// tiles of 64 (2 column-groups of 32 per tile).
__global__ __launch_bounds__(256, 2)
void vq_main(const float* __restrict__ z_e, const float* __restrict__ emb,
             const float* __restrict__ ws_norm, int* __restrict__ ws_flags,
             float* __restrict__ ws_loss, float* __restrict__ out) {
    // Double-buffered code tile, frag-ready: [buf][plane p][octet o][slot][8 bf16]
    // slot = code ^ (o<<1)  (bank-conflict swizzle on code bits 1-3)
    __shared__ unsigned short ldsB[2][3 * PLANE];  // 48 KB
    __shared__ int   fIdx[128];
    __shared__ float wsum[4];

    const int tid  = threadIdx.x;
    const int lane = tid & 63;
    const int wid  = tid >> 6;
    const int qbase = blockIdx.x * 128;
    const int b    = qbase >> 10;          // batch index (uniform per block)
    const int hwb  = qbase & (HW - 1);

    const int l31 = lane & 31;  // A: query row / B: code col / C-D: col
    const int kh  = lane >> 5;  // k-half: k = kk*16 + kh*8 + j

    // ---- Build A fragments from global (coalesced), split into 3 bf16 planes ----
    // A[row=l31][k = kk*16 + kh*8 + j]  -> dim d = kk*16 + kh*8 + j. afr[kk][plane]
    v8s afr[4][3];
    {
        const float* zb = z_e + b * (DIMS * HW);
        const int hwq = hwb + wid * 32 + l31;
#pragma unroll
        for (int kk = 0; kk < 4; ++kk) {
            int dbase = kk * 16 + kh * 8;
#pragma unroll
            for (int j = 0; j < 8; ++j) {
                float x = zb[(dbase + j) * HW + hwq];
                unsigned short h = f2bf(x);  float r1 = x - bf2f(h);
                unsigned short m = f2bf(r1); float r2 = r1 - bf2f(m);
                afr[kk][0][j] = (short)h;
                afr[kk][1][j] = (short)m;
                afr[kk][2][j] = (short)f2bf(r2);
            }
        }
    }

    // Per-lane best over its 16 C-rows (queries), reduced across lanes at end.
    float bestv[16];
    int   besti[16];
#pragma unroll
    for (int r = 0; r < 16; ++r) { bestv[r] = 3.4e38f; besti[r] = 0; }

    float4 regs[4];  // staging pipeline registers (16 fp32 = one 64-code tile / 256 thr)

    auto stage_loads = [&](int t) {
        const float4* src = (const float4*)(emb + t * 64 * DIMS);
#pragma unroll
        for (int i = 0; i < 4; ++i) regs[i] = src[tid + 256 * i];
    };
    auto stage_write = [&](int bb) {
        unsigned short* dst = &ldsB[bb][0];
#pragma unroll
        for (int i = 0; i < 4; ++i) {
            int e    = (tid + 256 * i) * 4;  // flat element in tile
            int code = e >> 6;
            int d    = e & 63;               // 4-aligned
            int o    = d >> 3;
            int sub  = d & 7;                // 0 or 4
            float xs[4] = {regs[i].x, regs[i].y, regs[i].z, regs[i].w};
            unsigned short h[4], mm_[4], l[4];
#pragma unroll
            for (int q = 0; q < 4; ++q) {
                float x = xs[q];
                unsigned short hh = f2bf(x);  float r1 = x - bf2f(hh);
                unsigned short mh = f2bf(r1); float r2 = r1 - bf2f(mh);
                h[q] = hh; mm_[q] = mh; l[q] = f2bf(r2);
            }
            int base = (o * 64 + (code ^ (o << 1))) * 8 + sub;  // swizzled slot
            uint2 uh, um, ul;
            uh.x = (unsigned)h[0]   | ((unsigned)h[1] << 16);
            uh.y = (unsigned)h[2]   | ((unsigned)h[3] << 16);
            um.x = (unsigned)mm_[0] | ((unsigned)mm_[1] << 16);
            um.y = (unsigned)mm_[2] | ((unsigned)mm_[3] << 16);
            ul.x = (unsigned)l[0]   | ((unsigned)l[1] << 16);
            ul.y = (unsigned)l[2]   | ((unsigned)l[3] << 16);
            *(uint2*)(dst + base)             = uh;
            *(uint2*)(dst + PLANE + base)     = um;
            *(uint2*)(dst + 2 * PLANE + base) = ul;
        }
    };

    stage_loads(0);
    stage_write(0);
    __syncthreads();

    for (int t = 0; t < 16; ++t) {
        const int cur = t & 1;
        if (t < 15) stage_loads(t + 1);
        const unsigned short* bufc = &ldsB[cur][0];
#pragma unroll
        for (int cg = 0; cg < 2; ++cg) {           // 32-code column groups
            const int ccol = cg * 32 + l31;        // code within tile
            float nrm = ws_norm[t * 64 + ccol];
            // B-frags: B[col=l31][k = kk*16 + kh*8 + j]; octet o = kk*2 + kh.
            v8s bfr[4][3];
#pragma unroll
            for (int kk = 0; kk < 4; ++kk) {
                int o    = kk * 2 + kh;
                int slot = ccol ^ (o << 1);
#pragma unroll
                for (int p = 0; p < 3; ++p)
                    bfr[kk][p] = *(const v8s*)(bufc + p * PLANE + (o * 64 + slot) * 8);
            }
            // Two independent 12-deep chains for ILP (kk01 -> aP, kk23 -> aQ).
            f32x16 aP = {0.f}, aQ = {0.f};
#pragma unroll
            for (int kk = 0; kk < 2; ++kk) {
                aP = MFMA32(afr[kk][0], bfr[kk][0], aP);      // hh
                aQ = MFMA32(afr[kk + 2][0], bfr[kk + 2][0], aQ);
                aP = MFMA32(afr[kk][0], bfr[kk][1], aP);      // hm
                aQ = MFMA32(afr[kk + 2][0], bfr[kk + 2][1], aQ);
                aP = MFMA32(afr[kk][1], bfr[kk][0], aP);      // mh
                aQ = MFMA32(afr[kk + 2][1], bfr[kk + 2][0], aQ);
                aP = MFMA32(afr[kk][1], bfr[kk][1], aP);      // mm
                aQ = MFMA32(afr[kk + 2][1], bfr[kk + 2][1], aQ);
                aP = MFMA32(afr[kk][0], bfr[kk][2], aP);      // hl
                aQ = MFMA32(afr[kk + 2][0], bfr[kk + 2][2], aQ);
                aP = MFMA32(afr[kk][2], bfr[kk][0], aP);      // lh
                aQ = MFMA32(afr[kk + 2][2], bfr[kk + 2][0], aQ);
            }
            int cbase = t * 64 + ccol;
#pragma unroll
            for (int r = 0; r < 16; ++r) {
                float dd = fmaf(-2.f, aQ[r], fmaf(-2.f, aP[r], nrm));
                if (dd < bestv[r]) { bestv[r] = dd; besti[r] = cbase; }
            }
        }
        if (t < 15) stage_write(1 - cur);  // other buffer: safe while peers finish cur
        __syncthreads();
    }

    // ---- Final argmin across the 32 code-columns held by this half-wave ----
    // C/D: col = lane&31, row = (r&3) + 8*(r>>2) + 4*kh. All 32 lanes of a
    // half share the same 16 rows; butterfly over 5 bits stays in-half.
#pragma unroll
    for (int r = 0; r < 16; ++r) {
        float v = bestv[r];
        int   idx = besti[r];
#pragma unroll
        for (int m = 16; m >= 1; m >>= 1) {
            float ov = __shfl_xor(v, m, 64);
            int   oi = __shfl_xor(idx, m, 64);
            if (ov < v || (ov == v && oi < idx)) { v = ov; idx = oi; }
        }
        if (l31 == 0) {
            int q = wid * 32 + (r & 3) + 8 * (r >> 2) + 4 * kh;  // within block
            fIdx[q] = idx;
            out[TOTAL_ELEMS + 1 + qbase + q] = (float)idx;
            ws_flags[idx] = 1;  // benign race
        }
    }
    __syncthreads();

    // ---- Gather z_q, write coalesced, accumulate mse partial ----
    const int q  = tid & 127;
    const int dh = tid >> 7;  // even/odd dims
    const int n  = qbase + q;
    const int bb = n >> 10;
    const int hw = n & (HW - 1);
    const int myIdx = fIdx[q];
    const float* erow = emb + myIdx * DIMS;
    float lsum = 0.f;
#pragma unroll
    for (int it = 0; it < 32; ++it) {
        int d = it * 2 + dh;
        float v = erow[d];                         // random row, L2/L3-resident
        int   o = bb * (DIMS * HW) + d * HW + hw;  // consecutive q -> coalesced
        float ze = z_e[o];
        out[o] = v;
        float df = ze - v;
        lsum = fmaf(df, df, lsum);
    }
#pragma unroll
    for (int off = 32; off > 0; off >>= 1) lsum += __shfl_down(lsum, off, 64);
    if (lane == 0) wsum[wid] = lsum;
    __syncthreads();
    if (tid == 0) atomicAdd(ws_loss, wsum[0] + wsum[1] + wsum[2] + wsum[3]);
}

// ---------------- Kernel C: finalize loss + usage ----------------
__global__ void vq_final(const int* __restrict__ flags, const float* __restrict__ loss,
                         float* __restrict__ out) {
    __shared__ int cnt[256];
    int tid = threadIdx.x;
    int c = flags[tid] + flags[tid + 256] + flags[tid + 512] + flags[tid + 768];
    cnt[tid] = c;
    __syncthreads();
    for (int s = 128; s > 0; s >>= 1) {
        if (tid < s) cnt[tid] += cnt[tid + s];
        __syncthreads();
    }
    if (tid == 0) {
        out[TOTAL_ELEMS] = *loss / (float)TOTAL_ELEMS;
        out[TOTAL_ELEMS + 1 + N_QUERIES] = (float)cnt[0] / (float)K_CODES;
    }
}

extern "C" void kernel_launch(void* const* d_in, const int* in_sizes, int n_in,
                              void* d_out, int out_size, void* d_ws, size_t ws_size,
                              hipStream_t stream) {
    const float* z_e = (const float*)d_in[0];
    const float* emb = (const float*)d_in[1];
    float* out = (float*)d_out;
    float* ws_norm  = (float*)d_ws;
    int*   ws_flags = (int*)((char*)d_ws + 4096);
    float* ws_loss  = (float*)((char*)d_ws + 8192);

    vq_prep<<<4, 256, 0, stream>>>(emb, ws_norm, ws_flags, ws_loss);
    vq_main<<<512, 256, 0, stream>>>(z_e, emb, ws_norm, ws_flags, ws_loss, out);
    vq_final<<<1, 256, 0, stream>>>(ws_flags, ws_loss, out);
}

// Round 9
// 123.859 us; speedup vs baseline: 1.3297x; 1.1194x over previous
//
#include <hip/hip_runtime.h>

// VQ-VAE eval forward, MFMA bf16x3-split path (fp32-faithful distances).
// B=64, D=64, H=32, W=32 -> N=65536 queries dim 64; K=1024 codes.
// dist(q,c) = ||e_c||^2 - 2 <x_q, e_c>  (||x||^2 dropped: per-query constant,
// fp32 add of a constant is monotonic -> argmin preserved incl. tie order).
// <x,e> via 6 bf16 MFMA products: x=xh+xm+xl exactly; keep hh,hm,mh,mm,hl,lh.
//
// R9 = R6 (76.0us vq_main; best) with the bf16x3 split arithmetic moved to
// v_cvt_pk_bf16_f32 (HW packed RNE convert, bit-identical to the manual RNE
// f2bf chain; result lands pre-packed for the 8B ds_writes). Cuts stage_write
// ~2x in VALU ops. Evidence: VALU is the largest busy pipe (26.4us); R7
// showed removing split VALU helps (-11us busy) but paying ws_split memory
// traffic costs more (+34us) -> cut the VALU in place instead.
// Lesson bank: 16x16x32 > 32x32x16 here (R8: 79.7 vs 76.0, MFMA not
// critical); bulk d_ws traffic in hot loop = +23..45us (R1/R2/R7); fused
// ticket finalize = +45us (R1/R2/R4/R5 vs R6); 2 blocks/CU required (R4).

#define DIMS 64
#define K_CODES 1024
#define N_QUERIES 65536
#define HW 1024
#define TOTAL_ELEMS 4194304
#define PLANE 4096  // shorts per plane in a code-tile buffer: 8 octets * 64 slots * 8

typedef __attribute__((ext_vector_type(8))) short v8s;   // 8 bf16 = 4 VGPR (A/B frag)
typedef __attribute__((ext_vector_type(4))) float f32x4; // C/D frag

// HW packed fp32->bf16 RNE convert: returns [bf16(hi)<<16 | bf16(lo)],
// i.e. shorts {lo, hi} in memory order. Bit-identical to manual RNE.
__device__ inline unsigned cvtpk(float lo, float hi) {
    unsigned r;
    asm("v_cvt_pk_bf16_f32 %0, %1, %2" : "=v"(r) : "v"(lo), "v"(hi));
    return r;
}
__device__ inline float lo2f(unsigned u) {  // bf16 in low half -> fp32
    union { unsigned u; float f; } v; v.u = u << 16; return v.f;
}
__device__ inline float hi2f(unsigned u) {  // bf16 in high half -> fp32
    union { unsigned u; float f; } v; v.u = u & 0xffff0000u; return v.f;
}

// ---------------- Kernel A: code norms + zero accumulators ----------------
__global__ void vq_prep(const float* __restrict__ emb, float* __restrict__ ws_norm,
                        int* __restrict__ ws_flags, float* __restrict__ ws_loss) {
    int k = blockIdx.x * 256 + threadIdx.x;  // 0..1023
    const float4* row = (const float4*)(emb + k * DIMS);
    float s = 0.f;
#pragma unroll
    for (int i = 0; i < 16; ++i) {
        float4 v = row[i];
        s += v.x * v.x + v.y * v.y + v.z * v.z + v.w * v.w;
    }
    ws_norm[k] = s;
    ws_flags[k] = 0;
    if (k == 0) *ws_loss = 0.f;
}

#define MFMA16(A_, B_, C_) __builtin_amdgcn_mfma_f32_16x16x32_bf16(A_, B_, C_, 0, 0, 0)

// ---------------- Kernel B: MFMA distances + argmin + gather + loss ----------------
// 512 blocks x 256 threads (4 waves), 2 blocks/CU. Block = 128 queries; wave =
// 32 queries (2 row-tiles of 16), each wave scans ALL 1024 codes in 16 tiles of 64.
__global__ __launch_bounds__(256, 2)
void vq_main(const float* __restrict__ z_e, const float* __restrict__ emb,
             const float* __restrict__ ws_norm, int* __restrict__ ws_flags,
             float* __restrict__ ws_loss, float* __restrict__ out) {
    // Double-buffered code tile, frag-ready: [buf][plane p][octet o][slot][8 bf16]
    // slot = code ^ (o<<1)  (bank-conflict swizzle on code bits 1-3)
    __shared__ unsigned short ldsB[2][3 * PLANE];  // 48 KB
    __shared__ int   fIdx[128];
    __shared__ float wsum[4];

    const int tid  = threadIdx.x;
    const int lane = tid & 63;
    const int wid  = tid >> 6;
    const int qbase = blockIdx.x * 128;
    const int b    = qbase >> 10;          // batch index (uniform per block)
    const int hwb  = qbase & (HW - 1);

    const int col  = lane & 15;  // m (A) / n (B) within 16-tile
    const int qd   = lane >> 4;  // quad -> k-octet selector

    // ---- Build A fragments from global (coalesced), split into 3 bf16 planes ----
    // A[m=col][k=qd*8+j]; dims d = kc*32 + qd*8 + j. afr[rt][kc][plane]
    v8s afr[2][2][3];
    {
        const float* zb = z_e + b * (DIMS * HW);
#pragma unroll
        for (int rt = 0; rt < 2; ++rt) {
            int hwq = hwb + wid * 32 + rt * 16 + col;
#pragma unroll
            for (int kc = 0; kc < 2; ++kc) {
                int dbase = kc * 32 + qd * 8;
                float x[8];
#pragma unroll
                for (int j = 0; j < 8; ++j) x[j] = zb[(dbase + j) * HW + hwq];
                unsigned* ah = (unsigned*)&afr[rt][kc][0];
                unsigned* am = (unsigned*)&afr[rt][kc][1];
                unsigned* al = (unsigned*)&afr[rt][kc][2];
#pragma unroll
                for (int j2 = 0; j2 < 4; ++j2) {
                    float xa = x[2 * j2], xb = x[2 * j2 + 1];
                    unsigned uh = cvtpk(xa, xb);
                    float ra = xa - lo2f(uh), rb = xb - hi2f(uh);
                    unsigned um = cvtpk(ra, rb);
                    float sa = ra - lo2f(um), sb = rb - hi2f(um);
                    ah[j2] = uh; am[j2] = um; al[j2] = cvtpk(sa, sb);
                }
            }
        }
    }

    float bestv[2][4];
    int   besti[2][4];
#pragma unroll
    for (int rt = 0; rt < 2; ++rt)
#pragma unroll
        for (int r = 0; r < 4; ++r) { bestv[rt][r] = 3.4e38f; besti[rt][r] = 0; }

    float4 regs[4];  // staging pipeline registers (16 fp32 = one 64-code tile / 256 thr)

    // Stage tile t's 64x64 fp32 into regs (fully coalesced: tile is contiguous).
    auto stage_loads = [&](int t) {
        const float4* src = (const float4*)(emb + t * 64 * DIMS);
#pragma unroll
        for (int i = 0; i < 4; ++i) regs[i] = src[tid + 256 * i];
    };
    // Split via cvt_pk + scatter into frag-ready LDS layout, swizzled (8B writes).
    auto stage_write = [&](int bb) {
        unsigned short* dst = &ldsB[bb][0];
#pragma unroll
        for (int i = 0; i < 4; ++i) {
            int e    = (tid + 256 * i) * 4;  // flat element in tile
            int code = e >> 6;
            int d    = e & 63;               // 4-aligned
            int o    = d >> 3;
            int sub  = d & 7;                // 0 or 4
            float x0 = regs[i].x, x1 = regs[i].y, x2 = regs[i].z, x3 = regs[i].w;
            unsigned uh0 = cvtpk(x0, x1), uh1 = cvtpk(x2, x3);
            float r10 = x0 - lo2f(uh0), r11 = x1 - hi2f(uh0);
            float r12 = x2 - lo2f(uh1), r13 = x3 - hi2f(uh1);
            unsigned um0 = cvtpk(r10, r11), um1 = cvtpk(r12, r13);
            float r20 = r10 - lo2f(um0), r21 = r11 - hi2f(um0);
            float r22 = r12 - lo2f(um1), r23 = r13 - hi2f(um1);
            unsigned ul0 = cvtpk(r20, r21), ul1 = cvtpk(r22, r23);
            int base = (o * 64 + (code ^ (o << 1))) * 8 + sub;  // swizzled slot
            uint2 uh = {uh0, uh1}, um = {um0, um1}, ul = {ul0, ul1};
            *(uint2*)(dst + base)             = uh;
            *(uint2*)(dst + PLANE + base)     = um;
            *(uint2*)(dst + 2 * PLANE + base) = ul;
        }
    };

    stage_loads(0);
    stage_write(0);
    __syncthreads();

    for (int t = 0; t < 16; ++t) {
        const int cur = t & 1;
        if (t < 15) stage_loads(t + 1);
        const unsigned short* bufc = &ldsB[cur][0];
#pragma unroll
        for (int cs = 0; cs < 4; ++cs) {
            float nrm = ws_norm[t * 64 + cs * 16 + col];
            // B-frags: B[n=col][k=qd*8+j], octet = kc*4+qd, swizzled slot.
            v8s bfr[2][3];
#pragma unroll
            for (int kc = 0; kc < 2; ++kc) {
                int oct  = kc * 4 + qd;
                int slot = (cs * 16 + col) ^ (oct << 1);
#pragma unroll
                for (int p = 0; p < 3; ++p)
                    bfr[kc][p] = *(const v8s*)(bufc + p * PLANE + (oct * 64 + slot) * 8);
            }
            f32x4 acc0 = {0.f, 0.f, 0.f, 0.f};
            f32x4 acc1 = {0.f, 0.f, 0.f, 0.f};
#pragma unroll
            for (int kc = 0; kc < 2; ++kc) {
                acc0 = MFMA16(afr[0][kc][0], bfr[kc][0], acc0);  // hh
                acc1 = MFMA16(afr[1][kc][0], bfr[kc][0], acc1);
                acc0 = MFMA16(afr[0][kc][0], bfr[kc][1], acc0);  // hm
                acc1 = MFMA16(afr[1][kc][0], bfr[kc][1], acc1);
                acc0 = MFMA16(afr[0][kc][1], bfr[kc][0], acc0);  // mh
                acc1 = MFMA16(afr[1][kc][1], bfr[kc][0], acc1);
                acc0 = MFMA16(afr[0][kc][1], bfr[kc][1], acc0);  // mm
                acc1 = MFMA16(afr[1][kc][1], bfr[kc][1], acc1);
                acc0 = MFMA16(afr[0][kc][0], bfr[kc][2], acc0);  // hl
                acc1 = MFMA16(afr[1][kc][0], bfr[kc][2], acc1);
                acc0 = MFMA16(afr[0][kc][2], bfr[kc][0], acc0);  // lh
                acc1 = MFMA16(afr[1][kc][2], bfr[kc][0], acc1);
            }
            int cbase = t * 64 + cs * 16 + col;
#pragma unroll
            for (int r = 0; r < 4; ++r) {
                float d0 = fmaf(-2.f, acc0[r], nrm);
                if (d0 < bestv[0][r]) { bestv[0][r] = d0; besti[0][r] = cbase; }
                float d1 = fmaf(-2.f, acc1[r], nrm);
                if (d1 < bestv[1][r]) { bestv[1][r] = d1; besti[1][r] = cbase; }
            }
        }
        if (t < 15) stage_write(1 - cur);  // other buffer: safe while peers finish cur
        __syncthreads();
    }

    // ---- Final argmin across the 16 columns held by this quad's lanes ----
    // C/D: row = qd*4 + r, col = lane&15. Lanes of a quad share rows, span cols.
#pragma unroll
    for (int rt = 0; rt < 2; ++rt)
#pragma unroll
    for (int r = 0; r < 4; ++r) {
        float v = bestv[rt][r];
        int   idx = besti[rt][r];
#pragma unroll
        for (int m = 8; m >= 1; m >>= 1) {
            float ov = __shfl_xor(v, m, 64);
            int   oi = __shfl_xor(idx, m, 64);
            if (ov < v || (ov == v && oi < idx)) { v = ov; idx = oi; }
        }
        if (col == 0) {
            int q = wid * 32 + rt * 16 + qd * 4 + r;  // within block
            fIdx[q] = idx;
            out[TOTAL_ELEMS + 1 + qbase + q] = (float)idx;
            ws_flags[idx] = 1;  // benign race
        }
    }
    __syncthreads();

    // ---- Gather z_q, write coalesced, accumulate mse partial ----
    const int q  = tid & 127;
    const int dh = tid >> 7;  // even/odd dims
    const int n  = qbase + q;
    const int bb = n >> 10;
    const int hw = n & (HW - 1);
    const int myIdx = fIdx[q];
    const float* erow = emb + myIdx * DIMS;
    float lsum = 0.f;
#pragma unroll
    for (int it = 0; it < 32; ++it) {
        int d = it * 2 + dh;
        float v = erow[d];                         // random row, L2/L3-resident
        int   o = bb * (DIMS * HW) + d * HW + hw;  // consecutive q -> coalesced
        float ze = z_e[o];
        out[o] = v;
        float df = ze - v;
        lsum = fmaf(df, df, lsum);
    }
#pragma unroll
    for (int off = 32; off > 0; off >>= 1) lsum += __shfl_down(lsum, off, 64);
    if (lane == 0) wsum[wid] = lsum;
    __syncthreads();
    if (tid == 0) atomicAdd(ws_loss, wsum[0] + wsum[1] + wsum[2] + wsum[3]);
}

// ---------------- Kernel C: finalize loss + usage ----------------
__global__ void vq_final(const int* __restrict__ flags, const float* __restrict__ loss,
                         float* __restrict__ out) {
    __shared__ int cnt[256];
    int tid = threadIdx.x;
    int c = flags[tid] + flags[tid + 256] + flags[tid + 512] + flags[tid + 768];
    cnt[tid] = c;
    __syncthreads();
    for (int s = 128; s > 0; s >>= 1) {
        if (tid < s) cnt[tid] += cnt[tid + s];
        __syncthreads();
    }
    if (tid == 0) {
        out[TOTAL_ELEMS] = *loss / (float)TOTAL_ELEMS;
        out[TOTAL_ELEMS + 1 + N_QUERIES] = (float)cnt[0] / (float)K_CODES;
    }
}

extern "C" void kernel_launch(void* const* d_in, const int* in_sizes, int n_in,
                              void* d_out, int out_size, void* d_ws, size_t ws_size,
                              hipStream_t stream) {
    const float* z_e = (const float*)d_in[0];
    const float* emb = (const float*)d_in[1];
    float* out = (float*)d_out;
    float* ws_norm  = (float*)d_ws;
    int*   ws_flags = (int*)((char*)d_ws + 4096);
    float* ws_loss  = (float*)((char*)d_ws + 8192);

    vq_prep<<<4, 256, 0, stream>>>(emb, ws_norm, ws_flags, ws_loss);
    vq_main<<<512, 256, 0, stream>>>(z_e, emb, ws_norm, ws_flags, ws_loss, out);
    vq_final<<<1, 256, 0, stream>>>(ws_flags, ws_loss, out);
}